// Round 1
// baseline (1015.164 us; speedup 1.0000x reference)
//
#include <hip/hip_runtime.h>
#include <math.h>

#define N_NODE 1024
#define NC 128            // b*d = 64*2
#define T_ALL 12
#define T1 11
#define NP 24             // period / number of graphs
#define NN (N_NODE*N_NODE)   // 1048576
#define HJ 72             // 3*H
#define HH 24             // H

// ---- workspace layout (float offsets) ----
#define WS_SC     0                                   // 12*1024*128 = 1572864
#define WS_COV    (WS_SC + T_ALL*N_NODE*NC)           // + 1048576
#define WS_MPART  (WS_COV + NN)                       // + 11*24*8 = 2112
#define WS_IDX    (WS_MPART + T1*NP*8)                // + 16 (ints)
#define WS_MEAN   (WS_IDX + 16)                       // + 1024
#define WS_GIPART (WS_MEAN + N_NODE)                  // + 128*72*12 = 110592
#define WS_GI     (WS_GIPART + 128*HJ*T_ALL)          // + 864

// ---------------------------------------------------------------------------
// K1: sc[t][n][c] = inputs[b][n][t][dd], c = b*2+dd
__global__ void k_build_sc(const float* __restrict__ inp, float* __restrict__ sc) {
    int i = blockIdx.x * 256 + threadIdx.x;          // < 1572864
    int t = i >> 17;
    int r = i & 131071;
    int n = r >> 7;
    int c = r & 127;
    int b = c >> 1, dd = c & 1;
    sc[i] = inp[(size_t)b * 24576 + (size_t)n * 24 + t * 2 + dd];
}

// ---------------------------------------------------------------------------
// K2: fused GEMM + masked abs-diff reduce.
// block: 256 threads; tile 128 rows (n) x 128 cols (c); K=1024 in steps of 32.
__global__ __launch_bounds__(256) void k_metrics(const float* __restrict__ G,
                                                 const float* __restrict__ sc,
                                                 float* __restrict__ mpart) {
    __shared__ float As[32 * 132];   // [kk][row], padded
    __shared__ float Bs[32 * 132];   // [kk][c], padded
    __shared__ float red[256];

    int nt = blockIdx.x;     // 0..7
    int p  = blockIdx.y;     // 0..23
    int t  = blockIdx.z;     // 0..10
    int tid = threadIdx.x;
    int tr = tid >> 4;       // 0..15 -> rows tr*8..+7
    int tc = tid & 15;       // 0..15 -> cols tc*8..+7
    int n0 = nt * 128;

    const float* Gp = G + (size_t)p * NN + (size_t)n0 * 1024;
    const float* Xt = sc + (size_t)t * (N_NODE * NC);

    float acc[8][8];
#pragma unroll
    for (int a = 0; a < 8; ++a)
#pragma unroll
        for (int b = 0; b < 8; ++b) acc[a][b] = 0.f;

    for (int ko = 0; ko < 1024; ko += 32) {
        // stage A tile transposed: As[kk][row]
#pragma unroll
        for (int it = 0; it < 4; ++it) {
            int fi = tid + it * 256;          // 0..1023
            int r = fi >> 3, q = fi & 7;
            float4 g4 = *(const float4*)(Gp + (size_t)r * 1024 + ko + q * 4);
            As[(q * 4 + 0) * 132 + r] = g4.x;
            As[(q * 4 + 1) * 132 + r] = g4.y;
            As[(q * 4 + 2) * 132 + r] = g4.z;
            As[(q * 4 + 3) * 132 + r] = g4.w;
        }
        // stage B tile: Bs[kk][c]
#pragma unroll
        for (int it = 0; it < 4; ++it) {
            int fi = tid + it * 256;
            int kk = fi >> 5, cq = fi & 31;
            float4 x4 = *(const float4*)(Xt + (size_t)(ko + kk) * 128 + cq * 4);
            *(float4*)(&Bs[kk * 132 + cq * 4]) = x4;
        }
        __syncthreads();
#pragma unroll
        for (int kk = 0; kk < 32; ++kk) {
            float4 a0 = *(const float4*)(&As[kk * 132 + tr * 8]);
            float4 a1 = *(const float4*)(&As[kk * 132 + tr * 8 + 4]);
            float4 b0 = *(const float4*)(&Bs[kk * 132 + tc * 8]);
            float4 b1 = *(const float4*)(&Bs[kk * 132 + tc * 8 + 4]);
            float a[8] = {a0.x, a0.y, a0.z, a0.w, a1.x, a1.y, a1.z, a1.w};
            float b[8] = {b0.x, b0.y, b0.z, b0.w, b1.x, b1.y, b1.z, b1.w};
#pragma unroll
            for (int rr = 0; rr < 8; ++rr)
#pragma unroll
                for (int cc = 0; cc < 8; ++cc)
                    acc[rr][cc] = fmaf(a[rr], b[cc], acc[rr][cc]);
        }
        __syncthreads();
    }

    // epilogue: masked |pred - target| partial sum
    const float* Tg = sc + (size_t)(t + 1) * (N_NODE * NC);
    float part = 0.f;
#pragma unroll
    for (int rr = 0; rr < 8; ++rr) {
        int n = n0 + tr * 8 + rr;
#pragma unroll
        for (int cc = 0; cc < 8; ++cc) {
            int c = tc * 8 + cc;
            float tg = Tg[(size_t)n * 128 + c];
            if (tg != 0.0f) part += fabsf(acc[rr][cc] - tg);
        }
    }
    red[tid] = part;
    __syncthreads();
    for (int s = 128; s > 0; s >>= 1) {
        if (tid < s) red[tid] += red[tid + s];
        __syncthreads();
    }
    if (tid == 0) mpart[((size_t)t * NP + p) * 8 + nt] = red[0];
}

// ---------------------------------------------------------------------------
// K2b: per-t argmin over p (first index on ties, matching jnp.argmin)
__global__ void k_argmin(const float* __restrict__ mpart, int* __restrict__ idx) {
    int t = blockIdx.x;      // 0..10
    int tid = threadIdx.x;   // 32
    __shared__ float m[NP];
    if (tid < NP) {
        float s = 0.f;
        for (int nt = 0; nt < 8; ++nt) s += mpart[((size_t)t * NP + tid) * 8 + nt];
        m[tid] = s;
    }
    __syncthreads();
    if (tid == 0) {
        int best = 0; float bv = m[0];
        for (int p = 1; p < NP; ++p)
            if (m[p] < bv) { bv = m[p]; best = p; }
        idx[t] = best;
    }
}

// ---------------------------------------------------------------------------
// K3a: per-row mean of last = sc[11]
__global__ void k_rowmean(const float* __restrict__ sc, float* __restrict__ meanv) {
    int r = blockIdx.x, c = threadIdx.x;   // grid 1024 x 128
    __shared__ float red[128];
    red[c] = sc[(size_t)11 * (N_NODE * NC) + (size_t)r * 128 + c];
    __syncthreads();
    for (int s = 64; s > 0; s >>= 1) {
        if (c < s) red[c] += red[c + s];
        __syncthreads();
    }
    if (c == 0) meanv[r] = red[0] * (1.0f / 128.0f);
}

// K3b: cov = xm @ xm.T / 127, 64x64 tiles, K=128
__global__ __launch_bounds__(256) void k_cov(const float* __restrict__ sc,
                                             const float* __restrict__ meanv,
                                             float* __restrict__ cov) {
    __shared__ float Ai[64 * 133];
    __shared__ float Bj[64 * 133];
    int bi = blockIdx.x, bj = blockIdx.y;    // 16 x 16
    int tid = threadIdx.x;
    int i0 = bi * 64, j0 = bj * 64;
    const float* L = sc + (size_t)11 * (N_NODE * NC);
#pragma unroll
    for (int it = 0; it < 8; ++it) {
        int fi = tid + it * 256;            // 0..2047
        int r = fi >> 5, q = fi & 31;
        float4 a4 = *(const float4*)(L + (size_t)(i0 + r) * 128 + q * 4);
        float ma = meanv[i0 + r];
        Ai[r * 133 + q * 4 + 0] = a4.x - ma;
        Ai[r * 133 + q * 4 + 1] = a4.y - ma;
        Ai[r * 133 + q * 4 + 2] = a4.z - ma;
        Ai[r * 133 + q * 4 + 3] = a4.w - ma;
        float4 b4 = *(const float4*)(L + (size_t)(j0 + r) * 128 + q * 4);
        float mb = meanv[j0 + r];
        Bj[r * 133 + q * 4 + 0] = b4.x - mb;
        Bj[r * 133 + q * 4 + 1] = b4.y - mb;
        Bj[r * 133 + q * 4 + 2] = b4.z - mb;
        Bj[r * 133 + q * 4 + 3] = b4.w - mb;
    }
    __syncthreads();
    int ti = tid >> 4, tj = tid & 15;
    float acc[4][4];
#pragma unroll
    for (int a = 0; a < 4; ++a)
#pragma unroll
        for (int b = 0; b < 4; ++b) acc[a][b] = 0.f;
    for (int k = 0; k < 128; ++k) {
        float a[4], b[4];
#pragma unroll
        for (int rr = 0; rr < 4; ++rr) a[rr] = Ai[(ti * 4 + rr) * 133 + k];
#pragma unroll
        for (int cc = 0; cc < 4; ++cc) b[cc] = Bj[(tj * 4 + cc) * 133 + k];
#pragma unroll
        for (int rr = 0; rr < 4; ++rr)
#pragma unroll
            for (int cc = 0; cc < 4; ++cc)
                acc[rr][cc] = fmaf(a[rr], b[cc], acc[rr][cc]);
    }
#pragma unroll
    for (int rr = 0; rr < 4; ++rr)
#pragma unroll
        for (int cc = 0; cc < 4; ++cc)
            cov[(size_t)(i0 + ti * 4 + rr) * 1024 + j0 + tj * 4 + cc] =
                acc[rr][cc] * (1.0f / 127.0f);
}

// ---------------------------------------------------------------------------
// K4: gi partials. grid (128 k-chunks, 9 j-groups); block 256 = 4 waves.
// wave w owns j-pair (jg*8 + w*2, +1); lane owns strided float4 k-slices.
__global__ __launch_bounds__(256) void k_gi_part(const float* __restrict__ Wih,
                                                 const float* __restrict__ G,
                                                 const float* __restrict__ cov,
                                                 const int* __restrict__ idx,
                                                 float* __restrict__ gipart) {
    int kc = blockIdx.x;          // 0..127 (chunk of 8192)
    int jg = blockIdx.y;          // 0..8
    int tid = threadIdx.x;
    int lane = tid & 63, wv = tid >> 6;
    int j0 = jg * 8 + wv * 2;

    const float* ctx[12];
#pragma unroll
    for (int t = 0; t < 11; ++t) ctx[t] = G + (size_t)idx[t] * NN;
    ctx[11] = cov;

    size_t kbase = (size_t)kc * 8192 + (size_t)lane * 4;
    const float* w0 = Wih + (size_t)j0 * NN;
    const float* w1 = Wih + (size_t)(j0 + 1) * NN;

    float acc[2][12];
#pragma unroll
    for (int j = 0; j < 2; ++j)
#pragma unroll
        for (int t = 0; t < 12; ++t) acc[j][t] = 0.f;

    for (int s = 0; s < 32; ++s) {
        size_t k = kbase + (size_t)s * 256;
        float4 wa = *(const float4*)(w0 + k);
        float4 wb = *(const float4*)(w1 + k);
#pragma unroll
        for (int t = 0; t < 12; ++t) {
            float4 x = *(const float4*)(ctx[t] + k);
            acc[0][t] += wa.x * x.x + wa.y * x.y + wa.z * x.z + wa.w * x.w;
            acc[1][t] += wb.x * x.x + wb.y * x.y + wb.z * x.z + wb.w * x.w;
        }
    }
#pragma unroll
    for (int j = 0; j < 2; ++j)
#pragma unroll
        for (int t = 0; t < 12; ++t) {
            float v = acc[j][t];
            for (int off = 32; off > 0; off >>= 1) v += __shfl_xor(v, off);
            if (lane == 0)
                gipart[((size_t)(j0 + j) * T_ALL + t) * 128 + kc] = v;
        }
}

// K4b: deterministic reduction of gi partials + bias
__global__ void k_gi_reduce(const float* __restrict__ gipart,
                            const float* __restrict__ bih,
                            float* __restrict__ gi) {
    int o = blockIdx.x * 256 + threadIdx.x;   // 0..863
    if (o >= HJ * T_ALL) return;
    int j = o / T_ALL, t = o % T_ALL;
    float s = 0.f;
    for (int kc = 0; kc < 128; ++kc) s += gipart[(size_t)o * 128 + kc];
    gi[(size_t)t * HJ + j] = s + bih[j];
}

// ---------------------------------------------------------------------------
// K5: GRU (12 steps, H=24) + argmax -> idx[11]
__global__ void k_gru(const float* __restrict__ gi, const float* __restrict__ Whh,
                      const float* __restrict__ bhh, int* __restrict__ idx) {
    __shared__ float h[HH], gh[HJ];
    int tid = threadIdx.x;   // 128
    if (tid < HH) h[tid] = 0.f;
    __syncthreads();
    for (int t = 0; t < T_ALL; ++t) {
        if (tid < HJ) {
            float s = bhh[tid];
            for (int k = 0; k < HH; ++k) s += Whh[tid * HH + k] * h[k];
            gh[tid] = s;
        }
        __syncthreads();
        if (tid < HH) {
            float gr = gi[t * HJ + tid];
            float gz = gi[t * HJ + 24 + tid];
            float gn = gi[t * HJ + 48 + tid];
            float r = 1.f / (1.f + expf(-(gr + gh[tid])));
            float z = 1.f / (1.f + expf(-(gz + gh[24 + tid])));
            float ng = tanhf(gn + r * gh[48 + tid]);
            h[tid] = (1.f - z) * ng + z * h[tid];
        }
        __syncthreads();
    }
    if (tid == 0) {
        int best = 0; float bv = h[0];
        for (int k = 1; k < HH; ++k)
            if (h[k] > bv) { bv = h[k]; best = k; }
        idx[11] = best;
    }
}

// ---------------------------------------------------------------------------
// K6: gather output rows
__global__ void k_gather(const float* __restrict__ G, const int* __restrict__ idx,
                         float4* __restrict__ out) {
    int i = blockIdx.x * 256 + threadIdx.x;      // float4 index, < 3145728
    int t = i >> 18;                              // / 262144
    int r = i & 262143;
    const float4* src = (const float4*)(G + (size_t)idx[t] * NN);
    out[i] = src[r];
}

// ---------------------------------------------------------------------------
extern "C" void kernel_launch(void* const* d_in, const int* in_sizes, int n_in,
                              void* d_out, int out_size, void* d_ws, size_t ws_size,
                              hipStream_t stream) {
    const float* inp = (const float*)d_in[0];
    const float* G   = (const float*)d_in[1];
    const float* Wih = (const float*)d_in[2];
    const float* Whh = (const float*)d_in[3];
    const float* bih = (const float*)d_in[4];
    const float* bhh = (const float*)d_in[5];

    float* ws = (float*)d_ws;
    float* sc     = ws + WS_SC;
    float* cov    = ws + WS_COV;
    float* mpart  = ws + WS_MPART;
    int*   idx    = (int*)(ws + WS_IDX);
    float* meanv  = ws + WS_MEAN;
    float* gipart = ws + WS_GIPART;
    float* gi     = ws + WS_GI;

    k_build_sc<<<6144, 256, 0, stream>>>(inp, sc);
    k_metrics<<<dim3(8, NP, T1), 256, 0, stream>>>(G, sc, mpart);
    k_argmin<<<T1, 32, 0, stream>>>(mpart, idx);
    k_rowmean<<<1024, 128, 0, stream>>>(sc, meanv);
    k_cov<<<dim3(16, 16), 256, 0, stream>>>(sc, meanv, cov);
    k_gi_part<<<dim3(128, 9), 256, 0, stream>>>(Wih, G, cov, idx, gipart);
    k_gi_reduce<<<4, 256, 0, stream>>>(gipart, bih, gi);
    k_gru<<<1, 128, 0, stream>>>(gi, Whh, bhh, idx);
    k_gather<<<12288, 256, 0, stream>>>(G, idx, (float4*)d_out);
}

// Round 2
// 426.868 us; speedup vs baseline: 2.3782x; 2.3782x over previous
//
#include <hip/hip_runtime.h>
#include <math.h>
#include <stdint.h>

#define N_NODE 1024
#define NC 128            // b*d = 64*2
#define T_ALL 12
#define T1 11
#define NP 24             // period / number of graphs
#define NN (N_NODE*N_NODE)   // 1048576
#define HJ 72             // 3*H
#define HH 24             // H

// ---- workspace layout (float offsets for legacy part) ----
#define WS_SC     0                                   // 12*1024*128 = 1572864
#define WS_COV    (WS_SC + T_ALL*N_NODE*NC)           // + 1048576
#define WS_MPART  (WS_COV + NN)                       // + 11*24*8 = 2112
#define WS_IDX    (WS_MPART + T1*NP*8)                // + 16 (ints)
#define WS_MEAN   (WS_IDX + 16)                       // + 1024
#define WS_GIPART (WS_MEAN + N_NODE)                  // + 128*72*12 = 110592
#define WS_GI     (WS_GIPART + 128*HJ*T_ALL)          // + 864
#define WS_BASE_FLOATS (WS_GI + HJ*T_ALL)             // = 2736064

// byte offsets for bf16 hi/lo tile arrays
#define AB_BASE_BYTES ((size_t)WS_BASE_FLOATS * 4)    // 10944256, 16B aligned
#define AHI_BYTES ((size_t)24*1024*1024*2)            // 50331648
#define BHI_BYTES ((size_t)11*32*4096*2)              // 2883584
#define WS_NEED_BYTES (AB_BASE_BYTES + 2*AHI_BYTES + 2*BHI_BYTES)  // 117374720

typedef __attribute__((ext_vector_type(8))) short short8v;
typedef __attribute__((ext_vector_type(8))) unsigned short ushort8v;
typedef __attribute__((ext_vector_type(4))) float f32x4;

// ---------------------------------------------------------------------------
__device__ __forceinline__ void gload16(const void* g, void* l) {
    __builtin_amdgcn_global_load_lds(
        (const __attribute__((address_space(1))) uint32_t*)g,
        (__attribute__((address_space(3))) uint32_t*)l, 16, 0, 0);
}

__device__ __forceinline__ void cvt_hilo(float f, unsigned short& h, unsigned short& l) {
    union { float f; uint32_t u; } a; a.f = f;
    uint32_t r = a.u + 0x7FFFu + ((a.u >> 16) & 1u);
    h = (unsigned short)(r >> 16);
    union { uint32_t u; float f; } hb; hb.u = ((uint32_t)h) << 16;
    float lo = f - hb.f;
    union { float f; uint32_t u; } b; b.f = lo;
    uint32_t r2 = b.u + 0x7FFFu + ((b.u >> 16) & 1u);
    l = (unsigned short)(r2 >> 16);
}

// ---------------------------------------------------------------------------
// K1: sc[t][n][c] = inputs[b][n][t][dd], c = b*2+dd
__global__ void k_build_sc(const float* __restrict__ inp, float* __restrict__ sc) {
    int i = blockIdx.x * 256 + threadIdx.x;          // < 1572864
    int t = i >> 17;
    int r = i & 131071;
    int n = r >> 7;
    int c = r & 127;
    int b = c >> 1, dd = c & 1;
    sc[i] = inp[(size_t)b * 24576 + (size_t)n * 24 + t * 2 + dd];
}

// ---------------------------------------------------------------------------
// Convert graphs -> tile-contiguous, XOR-swizzled bf16 hi/lo images.
// Tile (p,nt,ks) = G[p][nt*128..+128][ks*32..+32] stored as 4096 ushort:
//   byte_off(r,kk) = (r*64 + kk*2) ^ ((r&7)<<4)
__global__ __launch_bounds__(256) void k_cvt_A(const float* __restrict__ G,
                                               unsigned short* __restrict__ Ahi,
                                               unsigned short* __restrict__ Alo) {
    int tile = blockIdx.x;            // 0..6143 = (p*8+nt)*32+ks
    int ks = tile & 31;
    int pn = tile >> 5;
    int nt = pn & 7, p = pn >> 3;
    const float* Gt = G + (size_t)p * NN + (size_t)(nt * 128) * 1024 + ks * 32;
    size_t base = (size_t)tile * 4096;
#pragma unroll
    for (int g2 = 0; g2 < 2; ++g2) {
        int gid = threadIdx.x * 2 + g2;   // 0..511
        int r = gid >> 2, gg = gid & 3;
        const float* src = Gt + (size_t)r * 1024 + gg * 8;
        ushort8v h, l;
#pragma unroll
        for (int j = 0; j < 8; ++j) {
            unsigned short hh, ll;
            cvt_hilo(src[j], hh, ll);
            h[j] = hh; l[j] = ll;
        }
        int offu = ((r * 64 + gg * 16) ^ ((r & 7) << 4)) >> 1;  // ushort index
        *(ushort8v*)(Ahi + base + offu) = h;
        *(ushort8v*)(Alo + base + offu) = l;
    }
}

// Convert sc[t] (t<11) -> transposed [c][kk] swizzled bf16 tiles.
// Tile (t,ks): element (c,kk) = sc[t][ks*32+kk][c]; byte_off = (c*64+kk*2)^((c&7)<<4)
__global__ __launch_bounds__(256) void k_cvt_B(const float* __restrict__ sc,
                                               unsigned short* __restrict__ Bhi,
                                               unsigned short* __restrict__ Blo) {
    __shared__ float s[32][129];
    int tile = blockIdx.x;            // 0..351 = t*32+ks
    int ks = tile & 31;
    int t = tile >> 5;
    const float* S = sc + (size_t)t * (N_NODE * NC) + (size_t)ks * 32 * 128;
#pragma unroll
    for (int i = 0; i < 4; ++i) {
        int fi = threadIdx.x + i * 256;      // float4 index 0..1023
        int m = fi >> 5, c4 = fi & 31;
        float4 v = *(const float4*)(S + (size_t)m * 128 + c4 * 4);
        s[m][c4 * 4 + 0] = v.x;
        s[m][c4 * 4 + 1] = v.y;
        s[m][c4 * 4 + 2] = v.z;
        s[m][c4 * 4 + 3] = v.w;
    }
    __syncthreads();
    size_t base = (size_t)tile * 4096;
#pragma unroll
    for (int g2 = 0; g2 < 2; ++g2) {
        int gid = threadIdx.x * 2 + g2;   // 0..511
        int c = gid >> 2, gg = gid & 3;
        ushort8v h, l;
#pragma unroll
        for (int j = 0; j < 8; ++j) {
            unsigned short hh, ll;
            cvt_hilo(s[gg * 8 + j][c], hh, ll);
            h[j] = hh; l[j] = ll;
        }
        int offu = ((c * 64 + gg * 16) ^ ((c & 7) << 4)) >> 1;
        *(ushort8v*)(Bhi + base + offu) = h;
        *(ushort8v*)(Blo + base + offu) = l;
    }
}

// ---------------------------------------------------------------------------
// K2 (MFMA): bf16x3 GEMM + masked abs-diff reduce.
// grid (8 nt, 24 p, 11 t); block 256 = 4 waves (2x2); tile 128x128, BK=32.
__global__ __launch_bounds__(256) void k_metrics_mfma(
        const unsigned short* __restrict__ Ahi, const unsigned short* __restrict__ Alo,
        const unsigned short* __restrict__ Bhi, const unsigned short* __restrict__ Blo,
        const float* __restrict__ sc, float* __restrict__ mpart) {
    __shared__ unsigned short lds[4][4096];   // A_hi, A_lo, B_hi, B_lo (8KB each)
    __shared__ float red[256];

    int nt = blockIdx.x, p = blockIdx.y, t = blockIdx.z;
    int tid = threadIdx.x;
    int lane = tid & 63, wv = tid >> 6;
    int wr = wv >> 1, wc = wv & 1;
    int lr = lane & 15, lg = lane >> 4;

    size_t abase = (size_t)(p * 8 + nt) * 32 * 4096;
    size_t bbase = (size_t)t * 32 * 4096;
    const unsigned short* srcs = (wv == 0) ? Ahi + abase
                               : (wv == 1) ? Alo + abase
                               : (wv == 2) ? Bhi + bbase
                                           : Blo + bbase;
    unsigned short* ldsb = &lds[wv][0];

    f32x4 acc[4][4];
#pragma unroll
    for (int m = 0; m < 4; ++m)
#pragma unroll
        for (int n = 0; n < 4; ++n)
            acc[m][n] = (f32x4){0.f, 0.f, 0.f, 0.f};

    int aoff[4], boff[4];
#pragma unroll
    for (int m = 0; m < 4; ++m) {
        int row = wr * 64 + m * 16 + lr;
        aoff[m] = (row * 64 + lg * 16) ^ ((row & 7) << 4);
    }
#pragma unroll
    for (int n = 0; n < 4; ++n) {
        int col = wc * 64 + n * 16 + lr;
        boff[n] = (col * 64 + lg * 16) ^ ((col & 7) << 4);
    }

    const char* L0 = (const char*)&lds[0][0];
    const char* L1 = (const char*)&lds[1][0];
    const char* L2 = (const char*)&lds[2][0];
    const char* L3 = (const char*)&lds[3][0];

    for (int ks = 0; ks < 32; ++ks) {
        // stage: each wave copies its 8KB image linearly (source pre-swizzled)
        const unsigned short* sp = srcs + (size_t)ks * 4096;
#pragma unroll
        for (int i = 0; i < 8; ++i)
            gload16(sp + i * 512 + lane * 8, ldsb + i * 512);
        __syncthreads();

        short8v ah[4], al[4], bh[4], bl[4];
#pragma unroll
        for (int m = 0; m < 4; ++m) {
            ah[m] = *(const short8v*)(L0 + aoff[m]);
            al[m] = *(const short8v*)(L1 + aoff[m]);
        }
#pragma unroll
        for (int n = 0; n < 4; ++n) {
            bh[n] = *(const short8v*)(L2 + boff[n]);
            bl[n] = *(const short8v*)(L3 + boff[n]);
        }
#pragma unroll
        for (int m = 0; m < 4; ++m)
#pragma unroll
            for (int n = 0; n < 4; ++n) {
                acc[m][n] = __builtin_amdgcn_mfma_f32_16x16x32_bf16(ah[m], bh[n], acc[m][n], 0, 0, 0);
                acc[m][n] = __builtin_amdgcn_mfma_f32_16x16x32_bf16(ah[m], bl[n], acc[m][n], 0, 0, 0);
                acc[m][n] = __builtin_amdgcn_mfma_f32_16x16x32_bf16(al[m], bh[n], acc[m][n], 0, 0, 0);
            }
        __syncthreads();
    }

    // epilogue: masked |pred - target| partial sum
    // C/D layout: col = lane&15, row = (lane>>4)*4 + reg  [m89-verified]
    const float* Tg = sc + (size_t)(t + 1) * (N_NODE * NC);
    int n0 = nt * 128;
    float part = 0.f;
#pragma unroll
    for (int m = 0; m < 4; ++m)
#pragma unroll
        for (int j = 0; j < 4; ++j) {
            int row = wr * 64 + m * 16 + lg * 4 + j;
            const float* Trow = Tg + (size_t)(n0 + row) * 128 + wc * 64 + lr;
#pragma unroll
            for (int n = 0; n < 4; ++n) {
                float tg = Trow[n * 16];
                if (tg != 0.0f) part += fabsf(acc[m][n][j] - tg);
            }
        }
    red[tid] = part;
    __syncthreads();
    for (int s = 128; s > 0; s >>= 1) {
        if (tid < s) red[tid] += red[tid + s];
        __syncthreads();
    }
    if (tid == 0) mpart[((size_t)t * NP + p) * 8 + nt] = red[0];
}

// ---------------------------------------------------------------------------
// K2 (fp32 fallback, verified round 1)
__global__ __launch_bounds__(256) void k_metrics(const float* __restrict__ G,
                                                 const float* __restrict__ sc,
                                                 float* __restrict__ mpart) {
    __shared__ float As[32 * 132];
    __shared__ float Bs[32 * 132];
    __shared__ float red[256];

    int nt = blockIdx.x, p = blockIdx.y, t = blockIdx.z;
    int tid = threadIdx.x;
    int tr = tid >> 4, tc = tid & 15;
    int n0 = nt * 128;

    const float* Gp = G + (size_t)p * NN + (size_t)n0 * 1024;
    const float* Xt = sc + (size_t)t * (N_NODE * NC);

    float acc[8][8];
#pragma unroll
    for (int a = 0; a < 8; ++a)
#pragma unroll
        for (int b = 0; b < 8; ++b) acc[a][b] = 0.f;

    for (int ko = 0; ko < 1024; ko += 32) {
#pragma unroll
        for (int it = 0; it < 4; ++it) {
            int fi = tid + it * 256;
            int r = fi >> 3, q = fi & 7;
            float4 g4 = *(const float4*)(Gp + (size_t)r * 1024 + ko + q * 4);
            As[(q * 4 + 0) * 132 + r] = g4.x;
            As[(q * 4 + 1) * 132 + r] = g4.y;
            As[(q * 4 + 2) * 132 + r] = g4.z;
            As[(q * 4 + 3) * 132 + r] = g4.w;
        }
#pragma unroll
        for (int it = 0; it < 4; ++it) {
            int fi = tid + it * 256;
            int kk = fi >> 5, cq = fi & 31;
            float4 x4 = *(const float4*)(Xt + (size_t)(ko + kk) * 128 + cq * 4);
            *(float4*)(&Bs[kk * 132 + cq * 4]) = x4;
        }
        __syncthreads();
#pragma unroll
        for (int kk = 0; kk < 32; ++kk) {
            float4 a0 = *(const float4*)(&As[kk * 132 + tr * 8]);
            float4 a1 = *(const float4*)(&As[kk * 132 + tr * 8 + 4]);
            float4 b0 = *(const float4*)(&Bs[kk * 132 + tc * 8]);
            float4 b1 = *(const float4*)(&Bs[kk * 132 + tc * 8 + 4]);
            float a[8] = {a0.x, a0.y, a0.z, a0.w, a1.x, a1.y, a1.z, a1.w};
            float b[8] = {b0.x, b0.y, b0.z, b0.w, b1.x, b1.y, b1.z, b1.w};
#pragma unroll
            for (int rr = 0; rr < 8; ++rr)
#pragma unroll
                for (int cc = 0; cc < 8; ++cc)
                    acc[rr][cc] = fmaf(a[rr], b[cc], acc[rr][cc]);
        }
        __syncthreads();
    }

    const float* Tg = sc + (size_t)(t + 1) * (N_NODE * NC);
    float part = 0.f;
#pragma unroll
    for (int rr = 0; rr < 8; ++rr) {
        int n = n0 + tr * 8 + rr;
#pragma unroll
        for (int cc = 0; cc < 8; ++cc) {
            int c = tc * 8 + cc;
            float tg = Tg[(size_t)n * 128 + c];
            if (tg != 0.0f) part += fabsf(acc[rr][cc] - tg);
        }
    }
    red[tid] = part;
    __syncthreads();
    for (int s = 128; s > 0; s >>= 1) {
        if (tid < s) red[tid] += red[tid + s];
        __syncthreads();
    }
    if (tid == 0) mpart[((size_t)t * NP + p) * 8 + nt] = red[0];
}

// ---------------------------------------------------------------------------
// K2b: per-t argmin over p (first index on ties)
__global__ void k_argmin(const float* __restrict__ mpart, int* __restrict__ idx) {
    int t = blockIdx.x;
    int tid = threadIdx.x;
    __shared__ float m[NP];
    if (tid < NP) {
        float s = 0.f;
        for (int nt = 0; nt < 8; ++nt) s += mpart[((size_t)t * NP + tid) * 8 + nt];
        m[tid] = s;
    }
    __syncthreads();
    if (tid == 0) {
        int best = 0; float bv = m[0];
        for (int p = 1; p < NP; ++p)
            if (m[p] < bv) { bv = m[p]; best = p; }
        idx[t] = best;
    }
}

// ---------------------------------------------------------------------------
__global__ void k_rowmean(const float* __restrict__ sc, float* __restrict__ meanv) {
    int r = blockIdx.x, c = threadIdx.x;
    __shared__ float red[128];
    red[c] = sc[(size_t)11 * (N_NODE * NC) + (size_t)r * 128 + c];
    __syncthreads();
    for (int s = 64; s > 0; s >>= 1) {
        if (c < s) red[c] += red[c + s];
        __syncthreads();
    }
    if (c == 0) meanv[r] = red[0] * (1.0f / 128.0f);
}

__global__ __launch_bounds__(256) void k_cov(const float* __restrict__ sc,
                                             const float* __restrict__ meanv,
                                             float* __restrict__ cov) {
    __shared__ float Ai[64 * 133];
    __shared__ float Bj[64 * 133];
    int bi = blockIdx.x, bj = blockIdx.y;
    int tid = threadIdx.x;
    int i0 = bi * 64, j0 = bj * 64;
    const float* L = sc + (size_t)11 * (N_NODE * NC);
#pragma unroll
    for (int it = 0; it < 8; ++it) {
        int fi = tid + it * 256;
        int r = fi >> 5, q = fi & 31;
        float4 a4 = *(const float4*)(L + (size_t)(i0 + r) * 128 + q * 4);
        float ma = meanv[i0 + r];
        Ai[r * 133 + q * 4 + 0] = a4.x - ma;
        Ai[r * 133 + q * 4 + 1] = a4.y - ma;
        Ai[r * 133 + q * 4 + 2] = a4.z - ma;
        Ai[r * 133 + q * 4 + 3] = a4.w - ma;
        float4 b4 = *(const float4*)(L + (size_t)(j0 + r) * 128 + q * 4);
        float mb = meanv[j0 + r];
        Bj[r * 133 + q * 4 + 0] = b4.x - mb;
        Bj[r * 133 + q * 4 + 1] = b4.y - mb;
        Bj[r * 133 + q * 4 + 2] = b4.z - mb;
        Bj[r * 133 + q * 4 + 3] = b4.w - mb;
    }
    __syncthreads();
    int ti = tid >> 4, tj = tid & 15;
    float acc[4][4];
#pragma unroll
    for (int a = 0; a < 4; ++a)
#pragma unroll
        for (int b = 0; b < 4; ++b) acc[a][b] = 0.f;
    for (int k = 0; k < 128; ++k) {
        float a[4], b[4];
#pragma unroll
        for (int rr = 0; rr < 4; ++rr) a[rr] = Ai[(ti * 4 + rr) * 133 + k];
#pragma unroll
        for (int cc = 0; cc < 4; ++cc) b[cc] = Bj[(tj * 4 + cc) * 133 + k];
#pragma unroll
        for (int rr = 0; rr < 4; ++rr)
#pragma unroll
            for (int cc = 0; cc < 4; ++cc)
                acc[rr][cc] = fmaf(a[rr], b[cc], acc[rr][cc]);
    }
#pragma unroll
    for (int rr = 0; rr < 4; ++rr)
#pragma unroll
        for (int cc = 0; cc < 4; ++cc)
            cov[(size_t)(i0 + ti * 4 + rr) * 1024 + j0 + tj * 4 + cc] =
                acc[rr][cc] * (1.0f / 127.0f);
}

// ---------------------------------------------------------------------------
__global__ __launch_bounds__(256) void k_gi_part(const float* __restrict__ Wih,
                                                 const float* __restrict__ G,
                                                 const float* __restrict__ cov,
                                                 const int* __restrict__ idx,
                                                 float* __restrict__ gipart) {
    int kc = blockIdx.x;
    int jg = blockIdx.y;
    int tid = threadIdx.x;
    int lane = tid & 63, wv = tid >> 6;
    int j0 = jg * 8 + wv * 2;

    const float* ctx[12];
#pragma unroll
    for (int t = 0; t < 11; ++t) ctx[t] = G + (size_t)idx[t] * NN;
    ctx[11] = cov;

    size_t kbase = (size_t)kc * 8192 + (size_t)lane * 4;
    const float* w0 = Wih + (size_t)j0 * NN;
    const float* w1 = Wih + (size_t)(j0 + 1) * NN;

    float acc[2][12];
#pragma unroll
    for (int j = 0; j < 2; ++j)
#pragma unroll
        for (int t = 0; t < 12; ++t) acc[j][t] = 0.f;

    for (int s = 0; s < 32; ++s) {
        size_t k = kbase + (size_t)s * 256;
        float4 wa = *(const float4*)(w0 + k);
        float4 wb = *(const float4*)(w1 + k);
#pragma unroll
        for (int t = 0; t < 12; ++t) {
            float4 x = *(const float4*)(ctx[t] + k);
            acc[0][t] += wa.x * x.x + wa.y * x.y + wa.z * x.z + wa.w * x.w;
            acc[1][t] += wb.x * x.x + wb.y * x.y + wb.z * x.z + wb.w * x.w;
        }
    }
#pragma unroll
    for (int j = 0; j < 2; ++j)
#pragma unroll
        for (int t = 0; t < 12; ++t) {
            float v = acc[j][t];
            for (int off = 32; off > 0; off >>= 1) v += __shfl_xor(v, off);
            if (lane == 0)
                gipart[((size_t)(j0 + j) * T_ALL + t) * 128 + kc] = v;
        }
}

__global__ void k_gi_reduce(const float* __restrict__ gipart,
                            const float* __restrict__ bih,
                            float* __restrict__ gi) {
    int o = blockIdx.x * 256 + threadIdx.x;
    if (o >= HJ * T_ALL) return;
    int j = o / T_ALL, t = o % T_ALL;
    float s = 0.f;
    for (int kc = 0; kc < 128; ++kc) s += gipart[(size_t)o * 128 + kc];
    gi[(size_t)t * HJ + j] = s + bih[j];
}

// ---------------------------------------------------------------------------
__global__ void k_gru(const float* __restrict__ gi, const float* __restrict__ Whh,
                      const float* __restrict__ bhh, int* __restrict__ idx) {
    __shared__ float h[HH], gh[HJ];
    int tid = threadIdx.x;
    if (tid < HH) h[tid] = 0.f;
    __syncthreads();
    for (int t = 0; t < T_ALL; ++t) {
        if (tid < HJ) {
            float s = bhh[tid];
            for (int k = 0; k < HH; ++k) s += Whh[tid * HH + k] * h[k];
            gh[tid] = s;
        }
        __syncthreads();
        if (tid < HH) {
            float gr = gi[t * HJ + tid];
            float gz = gi[t * HJ + 24 + tid];
            float gn = gi[t * HJ + 48 + tid];
            float r = 1.f / (1.f + expf(-(gr + gh[tid])));
            float z = 1.f / (1.f + expf(-(gz + gh[24 + tid])));
            float ng = tanhf(gn + r * gh[48 + tid]);
            h[tid] = (1.f - z) * ng + z * h[tid];
        }
        __syncthreads();
    }
    if (tid == 0) {
        int best = 0; float bv = h[0];
        for (int k = 1; k < HH; ++k)
            if (h[k] > bv) { bv = h[k]; best = k; }
        idx[11] = best;
    }
}

// ---------------------------------------------------------------------------
__global__ void k_gather(const float* __restrict__ G, const int* __restrict__ idx,
                         float4* __restrict__ out) {
    int i = blockIdx.x * 256 + threadIdx.x;
    int t = i >> 18;
    int r = i & 262143;
    const float4* src = (const float4*)(G + (size_t)idx[t] * NN);
    out[i] = src[r];
}

// ---------------------------------------------------------------------------
extern "C" void kernel_launch(void* const* d_in, const int* in_sizes, int n_in,
                              void* d_out, int out_size, void* d_ws, size_t ws_size,
                              hipStream_t stream) {
    const float* inp = (const float*)d_in[0];
    const float* G   = (const float*)d_in[1];
    const float* Wih = (const float*)d_in[2];
    const float* Whh = (const float*)d_in[3];
    const float* bih = (const float*)d_in[4];
    const float* bhh = (const float*)d_in[5];

    float* ws = (float*)d_ws;
    float* sc     = ws + WS_SC;
    float* cov    = ws + WS_COV;
    float* mpart  = ws + WS_MPART;
    int*   idx    = (int*)(ws + WS_IDX);
    float* meanv  = ws + WS_MEAN;
    float* gipart = ws + WS_GIPART;
    float* gi     = ws + WS_GI;

    char* wsb = (char*)d_ws;
    unsigned short* Ahi = (unsigned short*)(wsb + AB_BASE_BYTES);
    unsigned short* Alo = (unsigned short*)(wsb + AB_BASE_BYTES + AHI_BYTES);
    unsigned short* Bhi = (unsigned short*)(wsb + AB_BASE_BYTES + 2 * AHI_BYTES);
    unsigned short* Blo = (unsigned short*)(wsb + AB_BASE_BYTES + 2 * AHI_BYTES + BHI_BYTES);

    bool use_mfma = (ws_size >= WS_NEED_BYTES);

    k_build_sc<<<6144, 256, 0, stream>>>(inp, sc);
    if (use_mfma) {
        k_cvt_A<<<6144, 256, 0, stream>>>(G, Ahi, Alo);
        k_cvt_B<<<352, 256, 0, stream>>>(sc, Bhi, Blo);
        k_metrics_mfma<<<dim3(8, NP, T1), 256, 0, stream>>>(Ahi, Alo, Bhi, Blo, sc, mpart);
    } else {
        k_metrics<<<dim3(8, NP, T1), 256, 0, stream>>>(G, sc, mpart);
    }
    k_argmin<<<T1, 32, 0, stream>>>(mpart, idx);
    k_rowmean<<<1024, 128, 0, stream>>>(sc, meanv);
    k_cov<<<dim3(16, 16), 256, 0, stream>>>(sc, meanv, cov);
    k_gi_part<<<dim3(128, 9), 256, 0, stream>>>(Wih, G, cov, idx, gipart);
    k_gi_reduce<<<4, 256, 0, stream>>>(gipart, bih, gi);
    k_gru<<<1, 128, 0, stream>>>(gi, Whh, bhh, idx);
    k_gather<<<12288, 256, 0, stream>>>(G, idx, (float4*)d_out);
}